// Round 7
// baseline (435.165 us; speedup 1.0000x reference)
//
#include <hip/hip_runtime.h>
#include <stdint.h>

typedef float f32x4 __attribute__((ext_vector_type(4)));
typedef short s16x8 __attribute__((ext_vector_type(8)));
typedef unsigned short u16x4 __attribute__((ext_vector_type(4)));

#define SCALE_F 0.08838834764831845f

__device__ __forceinline__ unsigned short f32_to_bf16(float f) {
    union { float f; unsigned int u; } v; v.f = f;
    return (unsigned short)((v.u + 0x7FFFu + ((v.u >> 16) & 1u)) >> 16);
}

__device__ __forceinline__ void gload16(const void* g, void* l) {
    __builtin_amdgcn_global_load_lds((const __attribute__((address_space(1))) unsigned int*)g,
                                     (__attribute__((address_space(3))) unsigned int*)l,
                                     16, 0, 0);
}

// ---------------- fp32 -> bf16 elementwise ----------------
__global__ void k_conv_bf16(const float* __restrict__ in, unsigned short* __restrict__ out, int n4) {
    int i = blockIdx.x * 256 + threadIdx.x;
    if (i >= n4) return;
    f32x4 v = ((const f32x4*)in)[i];
    u16x4 o;
    o[0] = f32_to_bf16(v[0]); o[1] = f32_to_bf16(v[1]);
    o[2] = f32_to_bf16(v[2]); o[3] = f32_to_bf16(v[3]);
    ((u16x4*)out)[i] = o;
}

// ------- fp32 [R][C] (row stride in_ld, col offset in_off) -> bf16 [C][R] -------
__global__ void k_transpose_bf16(const float* __restrict__ in, unsigned short* __restrict__ out,
                                 int R, int in_ld, int in_off) {
    __shared__ float tile[64][65];
    const int rb = blockIdx.y * 64, cb = blockIdx.x * 64;
    const int t = threadIdx.x;
    const int lr = t >> 4, lc4 = (t & 15) * 4;
#pragma unroll
    for (int i = 0; i < 4; ++i) {
        int r = i * 16 + lr;
        f32x4 v = *(const f32x4*)(in + (size_t)(rb + r) * in_ld + in_off + cb + lc4);
        tile[r][lc4 + 0] = v[0]; tile[r][lc4 + 1] = v[1];
        tile[r][lc4 + 2] = v[2]; tile[r][lc4 + 3] = v[3];
    }
    __syncthreads();
#pragma unroll
    for (int i = 0; i < 4; ++i) {
        int oc = cb + i * 16 + lr;
        u16x4 o;
#pragma unroll
        for (int j = 0; j < 4; ++j)
            o[j] = f32_to_bf16(tile[lc4 + j][i * 16 + lr]);
        *(u16x4*)(out + (size_t)oc * R + rb + lc4) = o;
    }
}

// ============ GEMM A: BM=256, BN=256, BK=64, 4 phases/tile, m201 discipline ============
// C[M][N] = A[M][K]*Bt[N][K]^T. 512 thr = 8 waves (2M x 4N), per-wave out 128x64.
// Phase = { ds_read frags; issue 1 stage; [vmcnt]; barrier; sched_barrier;
//           setprio(1); 16 MFMA; setprio(0); barrier }.
// vmcnt(4) at phases 1,3 only (guards next half-K's reads); grouped LDS = 0 conflicts.
__global__ __launch_bounds__(512, 1)
void k_gemmA(const unsigned short* __restrict__ A, const unsigned short* __restrict__ Bt,
             float* __restrict__ C, int N, int K) {
    __shared__ __align__(16) unsigned short As[2][2][8192];
    __shared__ __align__(16) unsigned short Bs[2][2][8192];
    const int tid = threadIdx.x;
    const int lane = tid & 63, wid = tid >> 6;
    const int g = lane >> 4, l15 = lane & 15;
    const int wm = wid >> 2, wn = wid & 3;
    const int nwg = gridDim.x, bid = blockIdx.x;
    const int swz = (bid & 7) * (nwg >> 3) + (bid >> 3);   // bijective: nwg % 8 == 0
    const int ntn = N >> 8;
    const int bm = swz / ntn, bn = swz - bm * ntn;
    const int brow = bm << 8, bcol = bn << 8;

    const int rowS = ((tid >> 6) << 4) | (tid & 15);
    const int kcS = (tid >> 4) & 3;
    const unsigned short* sA = A + (size_t)(brow + rowS) * K + kcS * 8;
    const unsigned short* sB = Bt + (size_t)(bcol + rowS) * K + kcS * 8;

    f32x4 acc[8][4] = {};
    const int nt = K >> 6;

    auto stA = [&](int t, int kh) {
        unsigned short* d = &As[t & 1][kh][tid * 8];
        const unsigned short* s = sA + (size_t)t * 64 + kh * 32;
        gload16(s, d);
        gload16(s + (size_t)128 * K, d + 4096);
    };
    auto stB = [&](int t, int kh) {
        unsigned short* d = &Bs[t & 1][kh][tid * 8];
        const unsigned short* s = sB + (size_t)t * 64 + kh * 32;
        gload16(s, d);
        gload16(s + (size_t)128 * K, d + 4096);
    };

    stA(0, 0); stB(0, 0); stA(0, 1); stB(0, 1);
    asm volatile("s_waitcnt vmcnt(4)" ::: "memory");
    __builtin_amdgcn_s_barrier();

    for (int t = 0; t < nt; ++t) {
        const int c = t & 1;
        s16x8 af[4], bf[4];
        // ---- P0: kh0 x rows 0-63 ----
#pragma unroll
        for (int f = 0; f < 4; ++f)
            af[f] = *(const s16x8*)(&As[c][0][((wm * 8 + f) * 64 + g * 16 + l15) * 8]);
#pragma unroll
        for (int j = 0; j < 4; ++j)
            bf[j] = *(const s16x8*)(&Bs[c][0][((wn * 4 + j) * 64 + g * 16 + l15) * 8]);
        if (t + 1 < nt) stA(t + 1, 0);
        __builtin_amdgcn_s_barrier();
        __builtin_amdgcn_sched_barrier(0);
        __builtin_amdgcn_s_setprio(1);
#pragma unroll
        for (int f = 0; f < 4; ++f)
#pragma unroll
            for (int j = 0; j < 4; ++j)
                acc[f][j] = __builtin_amdgcn_mfma_f32_16x16x32_bf16(af[f], bf[j], acc[f][j], 0, 0, 0);
        __builtin_amdgcn_s_setprio(0);
        __builtin_amdgcn_s_barrier();
        // ---- P1: kh0 x rows 64-127 (B frags live in regs) ----
#pragma unroll
        for (int f = 0; f < 4; ++f)
            af[f] = *(const s16x8*)(&As[c][0][((wm * 8 + 4 + f) * 64 + g * 16 + l15) * 8]);
        if (t + 1 < nt) { stB(t + 1, 0); asm volatile("s_waitcnt vmcnt(4)" ::: "memory"); }
        else            { asm volatile("s_waitcnt vmcnt(0)" ::: "memory"); }
        __builtin_amdgcn_s_barrier();
        __builtin_amdgcn_sched_barrier(0);
        __builtin_amdgcn_s_setprio(1);
#pragma unroll
        for (int f = 0; f < 4; ++f)
#pragma unroll
            for (int j = 0; j < 4; ++j)
                acc[4 + f][j] = __builtin_amdgcn_mfma_f32_16x16x32_bf16(af[f], bf[j], acc[4 + f][j], 0, 0, 0);
        __builtin_amdgcn_s_setprio(0);
        __builtin_amdgcn_s_barrier();
        // ---- P2: kh1 x rows 0-63 ----
#pragma unroll
        for (int f = 0; f < 4; ++f)
            af[f] = *(const s16x8*)(&As[c][1][((wm * 8 + f) * 64 + g * 16 + l15) * 8]);
#pragma unroll
        for (int j = 0; j < 4; ++j)
            bf[j] = *(const s16x8*)(&Bs[c][1][((wn * 4 + j) * 64 + g * 16 + l15) * 8]);
        if (t + 1 < nt) stA(t + 1, 1);
        __builtin_amdgcn_s_barrier();
        __builtin_amdgcn_sched_barrier(0);
        __builtin_amdgcn_s_setprio(1);
#pragma unroll
        for (int f = 0; f < 4; ++f)
#pragma unroll
            for (int j = 0; j < 4; ++j)
                acc[f][j] = __builtin_amdgcn_mfma_f32_16x16x32_bf16(af[f], bf[j], acc[f][j], 0, 0, 0);
        __builtin_amdgcn_s_setprio(0);
        __builtin_amdgcn_s_barrier();
        // ---- P3: kh1 x rows 64-127 ----
#pragma unroll
        for (int f = 0; f < 4; ++f)
            af[f] = *(const s16x8*)(&As[c][1][((wm * 8 + 4 + f) * 64 + g * 16 + l15) * 8]);
        if (t + 1 < nt) { stB(t + 1, 1); asm volatile("s_waitcnt vmcnt(4)" ::: "memory"); }
        __builtin_amdgcn_s_barrier();
        __builtin_amdgcn_sched_barrier(0);
        __builtin_amdgcn_s_setprio(1);
#pragma unroll
        for (int f = 0; f < 4; ++f)
#pragma unroll
            for (int j = 0; j < 4; ++j)
                acc[4 + f][j] = __builtin_amdgcn_mfma_f32_16x16x32_bf16(af[f], bf[j], acc[4 + f][j], 0, 0, 0);
        __builtin_amdgcn_s_setprio(0);
        __builtin_amdgcn_s_barrier();
    }

#pragma unroll
    for (int f = 0; f < 8; ++f)
#pragma unroll
        for (int j = 0; j < 4; ++j)
#pragma unroll
            for (int r = 0; r < 4; ++r)
                C[(size_t)(brow + wm * 128 + f * 16 + g * 4 + r) * N
                  + bcol + wn * 64 + j * 16 + l15] = acc[f][j][r];
}

// ============ GEMM B: BM=128, BN=256, BK=64, 2 phases/tile (full 256-wg fill) ============
// 512 thr = 8 waves (2M x 4N), per-wave out 64x64. vmcnt(3) per phase.
__global__ __launch_bounds__(512, 1)
void k_gemmB(const unsigned short* __restrict__ A, const unsigned short* __restrict__ Bt,
             float* __restrict__ C, int N, int K) {
    __shared__ __align__(16) unsigned short As[2][2][4096];
    __shared__ __align__(16) unsigned short Bs[2][2][8192];
    const int tid = threadIdx.x;
    const int lane = tid & 63, wid = tid >> 6;
    const int g = lane >> 4, l15 = lane & 15;
    const int wm = wid >> 2, wn = wid & 3;
    const int nwg = gridDim.x, bid = blockIdx.x;
    const int swz = (bid & 7) * (nwg >> 3) + (bid >> 3);
    const int ntn = N >> 8;
    const int bm = swz / ntn, bn = swz - bm * ntn;
    const int brow = bm << 7, bcol = bn << 8;

    const int rowS = ((tid >> 6) << 4) | (tid & 15);
    const int kcS = (tid >> 4) & 3;
    const unsigned short* sA = A + (size_t)(brow + rowS) * K + kcS * 8;
    const unsigned short* sB = Bt + (size_t)(bcol + rowS) * K + kcS * 8;

    f32x4 acc[4][4] = {};
    const int nt = K >> 6;

    auto stg = [&](int t, int kh) {
        unsigned short* dA = &As[t & 1][kh][tid * 8];
        unsigned short* dB = &Bs[t & 1][kh][tid * 8];
        const unsigned short* srcA = sA + (size_t)t * 64 + kh * 32;
        const unsigned short* srcB = sB + (size_t)t * 64 + kh * 32;
        gload16(srcA, dA);
        gload16(srcB, dB);
        gload16(srcB + (size_t)128 * K, dB + 4096);
    };

    stg(0, 0); stg(0, 1);
    asm volatile("s_waitcnt vmcnt(3)" ::: "memory");
    __builtin_amdgcn_s_barrier();

    for (int t = 0; t < nt; ++t) {
        const int c = t & 1;
#pragma unroll
        for (int kh = 0; kh < 2; ++kh) {
            s16x8 af[4], bf[4];
#pragma unroll
            for (int f = 0; f < 4; ++f)
                af[f] = *(const s16x8*)(&As[c][kh][((wm * 4 + f) * 64 + g * 16 + l15) * 8]);
#pragma unroll
            for (int j = 0; j < 4; ++j)
                bf[j] = *(const s16x8*)(&Bs[c][kh][((wn * 4 + j) * 64 + g * 16 + l15) * 8]);
            if (t + 1 < nt) { stg(t + 1, kh); asm volatile("s_waitcnt vmcnt(3)" ::: "memory"); }
            else if (kh == 0) { asm volatile("s_waitcnt vmcnt(0)" ::: "memory"); }
            __builtin_amdgcn_s_barrier();
            __builtin_amdgcn_sched_barrier(0);
            __builtin_amdgcn_s_setprio(1);
#pragma unroll
            for (int f = 0; f < 4; ++f)
#pragma unroll
                for (int j = 0; j < 4; ++j)
                    acc[f][j] = __builtin_amdgcn_mfma_f32_16x16x32_bf16(af[f], bf[j], acc[f][j], 0, 0, 0);
            __builtin_amdgcn_s_setprio(0);
            __builtin_amdgcn_s_barrier();
        }
    }

#pragma unroll
    for (int f = 0; f < 4; ++f)
#pragma unroll
        for (int j = 0; j < 4; ++j)
#pragma unroll
            for (int r = 0; r < 4; ++r)
                C[(size_t)(brow + wm * 64 + f * 16 + g * 4 + r) * N
                  + bcol + wn * 64 + j * 16 + l15] = acc[f][j][r];
}

// ---------------- RoPE + pack Q/K (V handled by transpose kernel) ----------------
__global__ void k_rope_pack(const float* __restrict__ qkv, const float* __restrict__ cosT,
                            const float* __restrict__ sinT, unsigned short* __restrict__ Qb,
                            unsigned short* __restrict__ Kb) {
    const int col = blockIdx.x * 256 + threadIdx.x;  // 0..5119
    const int t = blockIdx.y;
    const float v = qkv[(size_t)t * 6144 + col];
    const int d = col & 127;
    float o = v;
    if (d < 64) {
        float c = cosT[t * 64 + d], s = sinT[t * 64 + d];
        float partner = qkv[(size_t)t * 6144 + ((d < 32) ? col + 32 : col - 32)];
        o = (d < 32) ? (v * c - partner * s) : (v * c + partner * s);
    }
    unsigned short ob = f32_to_bf16(o);
    if (col < 4096) {
        int h = col >> 7;
        Qb[((size_t)h * 2048 + t) * 128 + d] = ob;
    } else {
        int hk = (col - 4096) >> 7;
        Kb[((size_t)hk * 2048 + t) * 128 + d] = ob;
    }
}

// ------- causal GQA flash attention: paired q-tiles (qbA, 31-qbA), shared K/V pass -------
__global__ __launch_bounds__(256, 2)
void k_attn(const unsigned short* __restrict__ Qb, const unsigned short* __restrict__ Kb,
            const unsigned short* __restrict__ Vt, unsigned short* __restrict__ Ob) {
    __shared__ __align__(16) unsigned short Ks[2][8192];
    __shared__ __align__(16) unsigned short Vs[2][8192];
    __shared__ __align__(16) unsigned short Pl[2][4][1024];
    const int h = blockIdx.y, hk = h >> 2;
    const int qbA = blockIdx.x, qbB = 31 - qbA;
    const int tid = threadIdx.x, lane = tid & 63, wid = tid >> 6;
    const int g = lane >> 4, l15 = lane & 15;
    const int qrA = qbA * 64 + wid * 16, qrB = qbB * 64 + wid * 16;
    const int swz = (l15 & 7) << 4;

    s16x8 aqA[4], aqB[4];
#pragma unroll
    for (int kc = 0; kc < 4; ++kc) {
        aqA[kc] = *(const s16x8*)(Qb + ((size_t)h * 2048 + qrA + l15) * 128 + kc * 32 + g * 8);
        aqB[kc] = *(const s16x8*)(Qb + ((size_t)h * 2048 + qrB + l15) * 128 + kc * 32 + g * 8);
    }

    const unsigned short* gK = Kb + ((size_t)hk * 2048 + (tid & 63)) * 128 + (tid >> 6) * 8;
    const unsigned short* gV = Vt + ((size_t)hk * 128 + (tid & 127)) * 2048 + (tid >> 7) * 8;

    auto stage = [&](int kb) {
        unsigned short* dK = Ks[kb & 1] + tid * 8;
        unsigned short* dV = Vs[kb & 1] + tid * 8;
        const unsigned short* sK = gK + (size_t)kb * 8192;
        const unsigned short* sV = gV + kb * 64;
#pragma unroll
        for (int i = 0; i < 4; ++i) gload16(sK + i * 32, dK + i * 2048);
#pragma unroll
        for (int i = 0; i < 4; ++i) gload16(sV + i * 16, dV + i * 2048);
    };

    f32x4 oaccA[8] = {}, oaccB[8] = {};
    float mA = -1e30f, lA = 0.f, mB = -1e30f, lB = 0.f;

    auto process = [&](const s16x8* aq, f32x4* oacc, float& mr, float& lr, int qrow0,
                       char* pw, const unsigned short* ks, const unsigned short* vs, int kb) {
        f32x4 s[4] = {};
#pragma unroll
        for (int kc = 0; kc < 4; ++kc)
#pragma unroll
            for (int kt = 0; kt < 4; ++kt) {
                s16x8 kf = *(const s16x8*)(ks + ((kc * 4 + g) * 64 + kt * 16 + l15) * 8);
                s[kt] = __builtin_amdgcn_mfma_f32_16x16x32_bf16(kf, aq[kc], s[kt], 0, 0, 0);
            }
        const int q = qrow0 + l15;
        if (kb * 64 + 63 > qrow0) {
#pragma unroll
            for (int kt = 0; kt < 4; ++kt)
#pragma unroll
                for (int r = 0; r < 4; ++r) {
                    float xv = s[kt][r] * SCALE_F;
                    s[kt][r] = (kb * 64 + kt * 16 + g * 4 + r > q) ? -3e38f : xv;
                }
        } else {
#pragma unroll
            for (int kt = 0; kt < 4; ++kt)
#pragma unroll
                for (int r = 0; r < 4; ++r) s[kt][r] *= SCALE_F;
        }
        float mx = -3e38f;
#pragma unroll
        for (int kt = 0; kt < 4; ++kt)
#pragma unroll
            for (int r = 0; r < 4; ++r) mx = fmaxf(mx, s[kt][r]);
        mx = fmaxf(mx, __shfl_xor(mx, 16));
        mx = fmaxf(mx, __shfl_xor(mx, 32));
        const float mnew = fmaxf(mr, mx);
        const float scal = __expf(mr - mnew);
        mr = mnew;
        float ps = 0.f;
#pragma unroll
        for (int kt = 0; kt < 4; ++kt)
#pragma unroll
            for (int r = 0; r < 4; ++r) {
                float p = __expf(s[kt][r] - mnew);
                s[kt][r] = p;
                ps += p;
            }
        ps += __shfl_xor(ps, 16);
        ps += __shfl_xor(ps, 32);
        lr = lr * scal + ps;
        float so[4];
#pragma unroll
        for (int r = 0; r < 4; ++r) so[r] = __shfl(scal, g * 4 + r, 16);
#pragma unroll
        for (int j = 0; j < 8; ++j) {
            oacc[j][0] *= so[0]; oacc[j][1] *= so[1];
            oacc[j][2] *= so[2]; oacc[j][3] *= so[3];
        }
#pragma unroll
        for (int kt = 0; kt < 4; ++kt) {
            unsigned int w0 = (unsigned int)f32_to_bf16(s[kt][0]) | ((unsigned int)f32_to_bf16(s[kt][1]) << 16);
            unsigned int w1 = (unsigned int)f32_to_bf16(s[kt][2]) | ((unsigned int)f32_to_bf16(s[kt][3]) << 16);
            const int b0 = (l15 * 128 + kt * 32 + g * 8) ^ swz;
            *(unsigned int*)(pw + b0) = w0;
            *(unsigned int*)(pw + b0 + 4) = w1;
        }
#pragma unroll
        for (int kc = 0; kc < 2; ++kc) {
            s16x8 pa = *(const s16x8*)(pw + ((l15 * 128 + kc * 64 + g * 16) ^ swz));
#pragma unroll
            for (int j = 0; j < 8; ++j) {
                s16x8 bv = *(const s16x8*)(vs + ((kc * 4 + g) * 128 + j * 16 + l15) * 8);
                oacc[j] = __builtin_amdgcn_mfma_f32_16x16x32_bf16(pa, bv, oacc[j], 0, 0, 0);
            }
        }
    };

    const int nkb = qbB + 1;
    stage(0);
    for (int kb = 0; kb < nkb; ++kb) {
        if (kb + 1 < nkb) {
            stage(kb + 1);
            asm volatile("s_waitcnt vmcnt(8)" ::: "memory");
        } else {
            asm volatile("s_waitcnt vmcnt(0)" ::: "memory");
        }
        __builtin_amdgcn_s_barrier();
        const unsigned short* ks = Ks[kb & 1];
        const unsigned short* vs = Vs[kb & 1];
        process(aqB, oaccB, mB, lB, qrB, (char*)Pl[1][wid], ks, vs, kb);
        if (kb <= qbA)
            process(aqA, oaccA, mA, lA, qrA, (char*)Pl[0][wid], ks, vs, kb);
        __builtin_amdgcn_s_barrier();
    }
    float liA[4], liB[4];
#pragma unroll
    for (int r = 0; r < 4; ++r) {
        liA[r] = 1.f / __shfl(lA, g * 4 + r, 16);
        liB[r] = 1.f / __shfl(lB, g * 4 + r, 16);
    }
#pragma unroll
    for (int j = 0; j < 8; ++j)
#pragma unroll
        for (int r = 0; r < 4; ++r) {
            Ob[(size_t)(qrA + g * 4 + r) * 4096 + h * 128 + j * 16 + l15] = f32_to_bf16(oaccA[j][r] * liA[r]);
            Ob[(size_t)(qrB + g * 4 + r) * 4096 + h * 128 + j * 16 + l15] = f32_to_bf16(oaccB[j][r] * liB[r]);
        }
}

extern "C" void kernel_launch(void* const* d_in, const int* in_sizes, int n_in,
                              void* d_out, int out_size, void* d_ws, size_t ws_size,
                              hipStream_t stream) {
    const float* x     = (const float*)d_in[0];
    const float* cosT  = (const float*)d_in[2];
    const float* sinT  = (const float*)d_in[3];
    const float* w_qkv = (const float*)d_in[4];
    const float* w_o   = (const float*)d_in[5];
    float* out = (float*)d_out;

    char* ws = (char*)d_ws;
    unsigned short* wT  = (unsigned short*)(ws + 0);
    float*          qkv = (float*)(ws + 50331648);
    unsigned short* Ob  = (unsigned short*)(ws + 50331648);
    unsigned short* xb  = (unsigned short*)(ws + 100663296);
    unsigned short* Qb  = xb;
    unsigned short* Kb  = (unsigned short*)(ws + 117440512);
    unsigned short* Vt  = (unsigned short*)(ws + 121634816);

    k_conv_bf16<<<8192, 256, 0, stream>>>(x, xb, 2097152);
    k_transpose_bf16<<<dim3(96, 64), 256, 0, stream>>>(w_qkv, wT, 4096, 6144, 0);
    k_gemmA<<<192, 512, 0, stream>>>(xb, wT, qkv, 6144, 4096);
    k_rope_pack<<<dim3(20, 2048), 256, 0, stream>>>(qkv, cosT, sinT, Qb, Kb);
    k_transpose_bf16<<<dim3(16, 32), 256, 0, stream>>>(qkv, Vt, 2048, 6144, 5120);   // V^T
    k_transpose_bf16<<<dim3(64, 64), 256, 0, stream>>>(w_o, wT, 4096, 4096, 0);
    k_attn<<<dim3(16, 32), 256, 0, stream>>>(Qb, Kb, Vt, Ob);
    k_gemmB<<<256, 512, 0, stream>>>(Ob, wT, out, 4096, 4096);
}

// Round 8
// 394.494 us; speedup vs baseline: 1.1031x; 1.1031x over previous
//
#include <hip/hip_runtime.h>
#include <stdint.h>

typedef float f32x4 __attribute__((ext_vector_type(4)));
typedef short s16x8 __attribute__((ext_vector_type(8)));
typedef unsigned short u16x4 __attribute__((ext_vector_type(4)));

#define SCALE_F 0.08838834764831845f

__device__ __forceinline__ unsigned short f32_to_bf16(float f) {
    union { float f; unsigned int u; } v; v.f = f;
    return (unsigned short)((v.u + 0x7FFFu + ((v.u >> 16) & 1u)) >> 16);
}

__device__ __forceinline__ void gload16(const void* g, void* l) {
    __builtin_amdgcn_global_load_lds((const __attribute__((address_space(1))) unsigned int*)g,
                                     (__attribute__((address_space(3))) unsigned int*)l,
                                     16, 0, 0);
}

// ---------------- fp32 -> bf16 elementwise ----------------
__global__ void k_conv_bf16(const float* __restrict__ in, unsigned short* __restrict__ out, int n4) {
    int i = blockIdx.x * 256 + threadIdx.x;
    if (i >= n4) return;
    f32x4 v = ((const f32x4*)in)[i];
    u16x4 o;
    o[0] = f32_to_bf16(v[0]); o[1] = f32_to_bf16(v[1]);
    o[2] = f32_to_bf16(v[2]); o[3] = f32_to_bf16(v[3]);
    ((u16x4*)out)[i] = o;
}

// ------- fp32 [R][C] (row stride in_ld, col offset in_off) -> bf16 [C][R] -------
__global__ void k_transpose_bf16(const float* __restrict__ in, unsigned short* __restrict__ out,
                                 int R, int in_ld, int in_off) {
    __shared__ float tile[64][65];
    const int rb = blockIdx.y * 64, cb = blockIdx.x * 64;
    const int t = threadIdx.x;
    const int lr = t >> 4, lc4 = (t & 15) * 4;
#pragma unroll
    for (int i = 0; i < 4; ++i) {
        int r = i * 16 + lr;
        f32x4 v = *(const f32x4*)(in + (size_t)(rb + r) * in_ld + in_off + cb + lc4);
        tile[r][lc4 + 0] = v[0]; tile[r][lc4 + 1] = v[1];
        tile[r][lc4 + 2] = v[2]; tile[r][lc4 + 3] = v[3];
    }
    __syncthreads();
#pragma unroll
    for (int i = 0; i < 4; ++i) {
        int oc = cb + i * 16 + lr;
        u16x4 o;
#pragma unroll
        for (int j = 0; j < 4; ++j)
            o[j] = f32_to_bf16(tile[lc4 + j][i * 16 + lr]);
        *(u16x4*)(out + (size_t)oc * R + rb + lc4) = o;
    }
}

// ---------------- K-half-phase pipelined bf16 GEMM (round-5 measured-best) ----------------
// C[M][N] = A[M][K] * Bt[N][K]^T.  BM=256, BK=64 (2 K-halves of 32), ring-2.
// LDS slot-swizzle: slot = kchunk ^ (row&3) ^ ((row>>2)&3); staging source pre-swizzled,
// frag-read offset is a per-thread constant. Loose schedule, counted vmcnt(6).
template<int BN>
__global__ __launch_bounds__(512, 1)
void k_gemm8p(const unsigned short* __restrict__ A, const unsigned short* __restrict__ Bt,
              float* __restrict__ C, int N, int K) {
    constexpr int BH = BN * 32;
    constexpr int NF = BN / 64;
    __shared__ __align__(16) unsigned short As[2][2][8192];
    __shared__ __align__(16) unsigned short Bs[2][2][BH];
    const int tid = threadIdx.x;
    const int lane = tid & 63, wid = tid >> 6;
    const int g = lane >> 4, l15 = lane & 15;
    const int wm = wid >> 2, wn = wid & 3;
    const int nwg = gridDim.x, bid = blockIdx.x;
    const int swz = (bid & 7) * (nwg >> 3) + (bid >> 3);   // bijective: nwg % 8 == 0
    const int ntn = N / BN;
    const int bm = swz / ntn, bn = swz - bm * ntn;
    const int brow = bm << 8, bcol = bn * BN;

    const int rS = tid >> 2;
    const int kcS = (tid & 3) ^ (rS & 3) ^ ((rS >> 2) & 3);
    const unsigned short* sA = A + (size_t)(brow + rS) * K + kcS * 8;
    const unsigned short* sB = Bt + (size_t)(bcol + rS) * K + kcS * 8;
    const int fsw = (g ^ (l15 & 3) ^ ((l15 >> 2) & 3)) * 8;

    f32x4 acc[8][NF] = {};
    const int nt = K >> 6;

    auto stA = [&](int t, int kh) {
        unsigned short* d = &As[t & 1][kh][tid * 8];
        const unsigned short* s = sA + (size_t)t * 64 + kh * 32;
        gload16(s, d);
        gload16(s + (size_t)128 * K, d + 4096);
    };
    auto stB = [&](int t, int kh) {
        unsigned short* d = &Bs[t & 1][kh][tid * 8];
        const unsigned short* s = sB + (size_t)t * 64 + kh * 32;
        gload16(s, d);
        if constexpr (BN == 256) gload16(s + (size_t)128 * K, d + 4096);
    };

    stA(0, 0); stB(0, 0); stA(0, 1); stB(0, 1);

    for (int t = 0; t < nt; ++t) {
        const int c = t & 1;
        if constexpr (BN == 256) {
            s16x8 af[4], bf[4];
            // ---- P0: kh0 x rows 0-63 ----
            if (t + 1 < nt) { stA(t + 1, 0); asm volatile("s_waitcnt vmcnt(6)" ::: "memory"); }
            else            { asm volatile("s_waitcnt vmcnt(4)" ::: "memory"); }
            __builtin_amdgcn_s_barrier();
#pragma unroll
            for (int f = 0; f < 4; ++f)
                af[f] = *(const s16x8*)(&As[c][0][(wm * 128 + f * 16 + l15) * 32 + fsw]);
#pragma unroll
            for (int j = 0; j < 4; ++j)
                bf[j] = *(const s16x8*)(&Bs[c][0][(wn * 64 + j * 16 + l15) * 32 + fsw]);
            __builtin_amdgcn_s_setprio(1);
#pragma unroll
            for (int f = 0; f < 4; ++f)
#pragma unroll
                for (int j = 0; j < 4; ++j)
                    acc[f][j] = __builtin_amdgcn_mfma_f32_16x16x32_bf16(af[f], bf[j], acc[f][j], 0, 0, 0);
            __builtin_amdgcn_s_setprio(0);
            // ---- P1: kh0 x rows 64-127 ----
            if (t + 1 < nt) stB(t + 1, 0);
#pragma unroll
            for (int f = 0; f < 4; ++f)
                af[f] = *(const s16x8*)(&As[c][0][(wm * 128 + 64 + f * 16 + l15) * 32 + fsw]);
            __builtin_amdgcn_s_setprio(1);
#pragma unroll
            for (int f = 0; f < 4; ++f)
#pragma unroll
                for (int j = 0; j < 4; ++j)
                    acc[4 + f][j] = __builtin_amdgcn_mfma_f32_16x16x32_bf16(af[f], bf[j], acc[4 + f][j], 0, 0, 0);
            __builtin_amdgcn_s_setprio(0);
            // ---- P2: kh1 x rows 0-63 ----
            if (t + 1 < nt) { stA(t + 1, 1); asm volatile("s_waitcnt vmcnt(6)" ::: "memory"); }
            else            { asm volatile("s_waitcnt vmcnt(0)" ::: "memory"); }
            __builtin_amdgcn_s_barrier();
#pragma unroll
            for (int f = 0; f < 4; ++f)
                af[f] = *(const s16x8*)(&As[c][1][(wm * 128 + f * 16 + l15) * 32 + fsw]);
#pragma unroll
            for (int j = 0; j < 4; ++j)
                bf[j] = *(const s16x8*)(&Bs[c][1][(wn * 64 + j * 16 + l15) * 32 + fsw]);
            __builtin_amdgcn_s_setprio(1);
#pragma unroll
            for (int f = 0; f < 4; ++f)
#pragma unroll
                for (int j = 0; j < 4; ++j)
                    acc[f][j] = __builtin_amdgcn_mfma_f32_16x16x32_bf16(af[f], bf[j], acc[f][j], 0, 0, 0);
            __builtin_amdgcn_s_setprio(0);
            // ---- P3: kh1 x rows 64-127 ----
            if (t + 1 < nt) stB(t + 1, 1);
#pragma unroll
            for (int f = 0; f < 4; ++f)
                af[f] = *(const s16x8*)(&As[c][1][(wm * 128 + 64 + f * 16 + l15) * 32 + fsw]);
            __builtin_amdgcn_s_setprio(1);
#pragma unroll
            for (int f = 0; f < 4; ++f)
#pragma unroll
                for (int j = 0; j < 4; ++j)
                    acc[4 + f][j] = __builtin_amdgcn_mfma_f32_16x16x32_bf16(af[f], bf[j], acc[4 + f][j], 0, 0, 0);
            __builtin_amdgcn_s_setprio(0);
        } else {
            s16x8 af[8], bf[2];
            // ---- P0: kh0, all 8 row-frags ----
            if (t + 1 < nt) { stA(t + 1, 0); stB(t + 1, 0); asm volatile("s_waitcnt vmcnt(6)" ::: "memory"); }
            else            { asm volatile("s_waitcnt vmcnt(3)" ::: "memory"); }
            __builtin_amdgcn_s_barrier();
#pragma unroll
            for (int f = 0; f < 8; ++f)
                af[f] = *(const s16x8*)(&As[c][0][(wm * 128 + f * 16 + l15) * 32 + fsw]);
#pragma unroll
            for (int j = 0; j < 2; ++j)
                bf[j] = *(const s16x8*)(&Bs[c][0][(wn * 32 + j * 16 + l15) * 32 + fsw]);
            __builtin_amdgcn_s_setprio(1);
#pragma unroll
            for (int f = 0; f < 8; ++f)
#pragma unroll
                for (int j = 0; j < 2; ++j)
                    acc[f][j] = __builtin_amdgcn_mfma_f32_16x16x32_bf16(af[f], bf[j], acc[f][j], 0, 0, 0);
            __builtin_amdgcn_s_setprio(0);
            // ---- P1: kh1 ----
            if (t + 1 < nt) { stA(t + 1, 1); stB(t + 1, 1); asm volatile("s_waitcnt vmcnt(6)" ::: "memory"); }
            else            { asm volatile("s_waitcnt vmcnt(0)" ::: "memory"); }
            __builtin_amdgcn_s_barrier();
#pragma unroll
            for (int f = 0; f < 8; ++f)
                af[f] = *(const s16x8*)(&As[c][1][(wm * 128 + f * 16 + l15) * 32 + fsw]);
#pragma unroll
            for (int j = 0; j < 2; ++j)
                bf[j] = *(const s16x8*)(&Bs[c][1][(wn * 32 + j * 16 + l15) * 32 + fsw]);
            __builtin_amdgcn_s_setprio(1);
#pragma unroll
            for (int f = 0; f < 8; ++f)
#pragma unroll
                for (int j = 0; j < 2; ++j)
                    acc[f][j] = __builtin_amdgcn_mfma_f32_16x16x32_bf16(af[f], bf[j], acc[f][j], 0, 0, 0);
            __builtin_amdgcn_s_setprio(0);
        }
    }

#pragma unroll
    for (int f = 0; f < 8; ++f)
#pragma unroll
        for (int j = 0; j < NF; ++j)
#pragma unroll
            for (int r = 0; r < 4; ++r)
                C[(size_t)(brow + wm * 128 + f * 16 + g * 4 + r) * N
                  + bcol + wn * (BN / 4) + j * 16 + l15] = acc[f][j][r];
}

// ---------------- RoPE + pack Q/K (V handled by transpose kernel) ----------------
__global__ void k_rope_pack(const float* __restrict__ qkv, const float* __restrict__ cosT,
                            const float* __restrict__ sinT, unsigned short* __restrict__ Qb,
                            unsigned short* __restrict__ Kb) {
    const int col = blockIdx.x * 256 + threadIdx.x;  // 0..5119
    const int t = blockIdx.y;
    const float v = qkv[(size_t)t * 6144 + col];
    const int d = col & 127;
    float o = v;
    if (d < 64) {
        float c = cosT[t * 64 + d], s = sinT[t * 64 + d];
        float partner = qkv[(size_t)t * 6144 + ((d < 32) ? col + 32 : col - 32)];
        o = (d < 32) ? (v * c - partner * s) : (v * c + partner * s);
    }
    unsigned short ob = f32_to_bf16(o);
    if (col < 4096) {
        int h = col >> 7;
        Qb[((size_t)h * 2048 + t) * 128 + d] = ob;
    } else {
        int hk = (col - 4096) >> 7;
        Kb[((size_t)hk * 2048 + t) * 128 + d] = ob;
    }
}

// ------- causal GQA flash attention: paired q-tiles (qbA, 31-qbA), shared K/V pass -------
// + T13 defer-max: skip O-rescale when tile max stays within 8 of running max.
__global__ __launch_bounds__(256, 2)
void k_attn(const unsigned short* __restrict__ Qb, const unsigned short* __restrict__ Kb,
            const unsigned short* __restrict__ Vt, unsigned short* __restrict__ Ob) {
    __shared__ __align__(16) unsigned short Ks[2][8192];
    __shared__ __align__(16) unsigned short Vs[2][8192];
    __shared__ __align__(16) unsigned short Pl[2][4][1024];
    const int h = blockIdx.y, hk = h >> 2;
    const int qbA = blockIdx.x, qbB = 31 - qbA;
    const int tid = threadIdx.x, lane = tid & 63, wid = tid >> 6;
    const int g = lane >> 4, l15 = lane & 15;
    const int qrA = qbA * 64 + wid * 16, qrB = qbB * 64 + wid * 16;
    const int swz = (l15 & 7) << 4;

    s16x8 aqA[4], aqB[4];
#pragma unroll
    for (int kc = 0; kc < 4; ++kc) {
        aqA[kc] = *(const s16x8*)(Qb + ((size_t)h * 2048 + qrA + l15) * 128 + kc * 32 + g * 8);
        aqB[kc] = *(const s16x8*)(Qb + ((size_t)h * 2048 + qrB + l15) * 128 + kc * 32 + g * 8);
    }

    const unsigned short* gK = Kb + ((size_t)hk * 2048 + (tid & 63)) * 128 + (tid >> 6) * 8;
    const unsigned short* gV = Vt + ((size_t)hk * 128 + (tid & 127)) * 2048 + (tid >> 7) * 8;

    auto stage = [&](int kb) {
        unsigned short* dK = Ks[kb & 1] + tid * 8;
        unsigned short* dV = Vs[kb & 1] + tid * 8;
        const unsigned short* sK = gK + (size_t)kb * 8192;
        const unsigned short* sV = gV + kb * 64;
#pragma unroll
        for (int i = 0; i < 4; ++i) gload16(sK + i * 32, dK + i * 2048);
#pragma unroll
        for (int i = 0; i < 4; ++i) gload16(sV + i * 16, dV + i * 2048);
    };

    f32x4 oaccA[8] = {}, oaccB[8] = {};
    float mA = -1e30f, lA = 0.f, mB = -1e30f, lB = 0.f;

    auto process = [&](const s16x8* aq, f32x4* oacc, float& mr, float& lr, int qrow0,
                       char* pw, const unsigned short* ks, const unsigned short* vs, int kb) {
        f32x4 s[4] = {};
#pragma unroll
        for (int kc = 0; kc < 4; ++kc)
#pragma unroll
            for (int kt = 0; kt < 4; ++kt) {
                s16x8 kf = *(const s16x8*)(ks + ((kc * 4 + g) * 64 + kt * 16 + l15) * 8);
                s[kt] = __builtin_amdgcn_mfma_f32_16x16x32_bf16(kf, aq[kc], s[kt], 0, 0, 0);
            }
        const int q = qrow0 + l15;
        if (kb * 64 + 63 > qrow0) {
#pragma unroll
            for (int kt = 0; kt < 4; ++kt)
#pragma unroll
                for (int r = 0; r < 4; ++r) {
                    float xv = s[kt][r] * SCALE_F;
                    s[kt][r] = (kb * 64 + kt * 16 + g * 4 + r > q) ? -3e38f : xv;
                }
        } else {
#pragma unroll
            for (int kt = 0; kt < 4; ++kt)
#pragma unroll
                for (int r = 0; r < 4; ++r) s[kt][r] *= SCALE_F;
        }
        float mx = -3e38f;
#pragma unroll
        for (int kt = 0; kt < 4; ++kt)
#pragma unroll
            for (int r = 0; r < 4; ++r) mx = fmaxf(mx, s[kt][r]);
        mx = fmaxf(mx, __shfl_xor(mx, 16));
        mx = fmaxf(mx, __shfl_xor(mx, 32));
        // T13 defer-max: only rescale when the new tile max exceeds m+8.
        if (!__all(mx - mr <= 8.0f)) {
            const float mnew = fmaxf(mr, mx);
            const float scal = __expf(mr - mnew);
            mr = mnew;
            float so[4];
#pragma unroll
            for (int r = 0; r < 4; ++r) so[r] = __shfl(scal, g * 4 + r, 16);
#pragma unroll
            for (int j = 0; j < 8; ++j) {
                oacc[j][0] *= so[0]; oacc[j][1] *= so[1];
                oacc[j][2] *= so[2]; oacc[j][3] *= so[3];
            }
            lr *= scal;
        }
        float ps = 0.f;
#pragma unroll
        for (int kt = 0; kt < 4; ++kt)
#pragma unroll
            for (int r = 0; r < 4; ++r) {
                float p = __expf(s[kt][r] - mr);
                s[kt][r] = p;
                ps += p;
            }
        ps += __shfl_xor(ps, 16);
        ps += __shfl_xor(ps, 32);
        lr += ps;
#pragma unroll
        for (int kt = 0; kt < 4; ++kt) {
            unsigned int w0 = (unsigned int)f32_to_bf16(s[kt][0]) | ((unsigned int)f32_to_bf16(s[kt][1]) << 16);
            unsigned int w1 = (unsigned int)f32_to_bf16(s[kt][2]) | ((unsigned int)f32_to_bf16(s[kt][3]) << 16);
            const int b0 = (l15 * 128 + kt * 32 + g * 8) ^ swz;
            *(unsigned int*)(pw + b0) = w0;
            *(unsigned int*)(pw + b0 + 4) = w1;
        }
#pragma unroll
        for (int kc = 0; kc < 2; ++kc) {
            s16x8 pa = *(const s16x8*)(pw + ((l15 * 128 + kc * 64 + g * 16) ^ swz));
#pragma unroll
            for (int j = 0; j < 8; ++j) {
                s16x8 bv = *(const s16x8*)(vs + ((kc * 4 + g) * 128 + j * 16 + l15) * 8);
                oacc[j] = __builtin_amdgcn_mfma_f32_16x16x32_bf16(pa, bv, oacc[j], 0, 0, 0);
            }
        }
    };

    const int nkb = qbB + 1;
    stage(0);
    for (int kb = 0; kb < nkb; ++kb) {
        if (kb + 1 < nkb) {
            stage(kb + 1);
            asm volatile("s_waitcnt vmcnt(8)" ::: "memory");
        } else {
            asm volatile("s_waitcnt vmcnt(0)" ::: "memory");
        }
        __builtin_amdgcn_s_barrier();
        const unsigned short* ks = Ks[kb & 1];
        const unsigned short* vs = Vs[kb & 1];
        process(aqB, oaccB, mB, lB, qrB, (char*)Pl[1][wid], ks, vs, kb);
        if (kb <= qbA)
            process(aqA, oaccA, mA, lA, qrA, (char*)Pl[0][wid], ks, vs, kb);
        __builtin_amdgcn_s_barrier();
    }
    float liA[4], liB[4];
#pragma unroll
    for (int r = 0; r < 4; ++r) {
        liA[r] = 1.f / __shfl(lA, g * 4 + r, 16);
        liB[r] = 1.f / __shfl(lB, g * 4 + r, 16);
    }
#pragma unroll
    for (int j = 0; j < 8; ++j)
#pragma unroll
        for (int r = 0; r < 4; ++r) {
            Ob[(size_t)(qrA + g * 4 + r) * 4096 + h * 128 + j * 16 + l15] = f32_to_bf16(oaccA[j][r] * liA[r]);
            Ob[(size_t)(qrB + g * 4 + r) * 4096 + h * 128 + j * 16 + l15] = f32_to_bf16(oaccB[j][r] * liB[r]);
        }
}

extern "C" void kernel_launch(void* const* d_in, const int* in_sizes, int n_in,
                              void* d_out, int out_size, void* d_ws, size_t ws_size,
                              hipStream_t stream) {
    const float* x     = (const float*)d_in[0];
    const float* cosT  = (const float*)d_in[2];
    const float* sinT  = (const float*)d_in[3];
    const float* w_qkv = (const float*)d_in[4];
    const float* w_o   = (const float*)d_in[5];
    float* out = (float*)d_out;

    char* ws = (char*)d_ws;
    unsigned short* wT  = (unsigned short*)(ws + 0);
    float*          qkv = (float*)(ws + 50331648);
    unsigned short* Ob  = (unsigned short*)(ws + 50331648);
    unsigned short* xb  = (unsigned short*)(ws + 100663296);
    unsigned short* Qb  = xb;
    unsigned short* Kb  = (unsigned short*)(ws + 117440512);
    unsigned short* Vt  = (unsigned short*)(ws + 121634816);

    k_conv_bf16<<<8192, 256, 0, stream>>>(x, xb, 2097152);
    k_transpose_bf16<<<dim3(96, 64), 256, 0, stream>>>(w_qkv, wT, 4096, 6144, 0);
    k_gemm8p<256><<<192, 512, 0, stream>>>(xb, wT, qkv, 6144, 4096);
    k_rope_pack<<<dim3(20, 2048), 256, 0, stream>>>(qkv, cosT, sinT, Qb, Kb);
    k_transpose_bf16<<<dim3(16, 32), 256, 0, stream>>>(qkv, Vt, 2048, 6144, 5120);   // V^T
    k_transpose_bf16<<<dim3(64, 64), 256, 0, stream>>>(w_o, wT, 4096, 4096, 0);
    k_attn<<<dim3(16, 32), 256, 0, stream>>>(Qb, Kb, Vt, Ob);
    k_gemm8p<128><<<256, 512, 0, stream>>>(Ob, wT, out, 4096, 4096);
}

// Round 9
// 363.586 us; speedup vs baseline: 1.1969x; 1.0850x over previous
//
#include <hip/hip_runtime.h>
#include <stdint.h>

typedef float f32x4 __attribute__((ext_vector_type(4)));
typedef short s16x8 __attribute__((ext_vector_type(8)));
typedef unsigned short u16x4 __attribute__((ext_vector_type(4)));
typedef unsigned short u16x8 __attribute__((ext_vector_type(8)));

#define SCALE_F 0.08838834764831845f

__device__ __forceinline__ unsigned short f32_to_bf16(float f) {
    union { float f; unsigned int u; } v; v.f = f;
    return (unsigned short)((v.u + 0x7FFFu + ((v.u >> 16) & 1u)) >> 16);
}
__device__ __forceinline__ float bf16_to_f32(unsigned short h) {
    union { unsigned int u; float f; } v; v.u = (unsigned int)h << 16;
    return v.f;
}

__device__ __forceinline__ void gload16(const void* g, void* l) {
    __builtin_amdgcn_global_load_lds((const __attribute__((address_space(1))) unsigned int*)g,
                                     (__attribute__((address_space(3))) unsigned int*)l,
                                     16, 0, 0);
}

// ---------------- fp32 -> bf16 elementwise ----------------
__global__ void k_conv_bf16(const float* __restrict__ in, unsigned short* __restrict__ out, int n4) {
    int i = blockIdx.x * 256 + threadIdx.x;
    if (i >= n4) return;
    f32x4 v = ((const f32x4*)in)[i];
    u16x4 o;
    o[0] = f32_to_bf16(v[0]); o[1] = f32_to_bf16(v[1]);
    o[2] = f32_to_bf16(v[2]); o[3] = f32_to_bf16(v[3]);
    ((u16x4*)out)[i] = o;
}

// ------- fp32 [R][in_ld] (col offset in_off) -> bf16 [C][R] -------
__global__ void k_transpose_f32(const float* __restrict__ in, unsigned short* __restrict__ out,
                                int R, int in_ld, int in_off) {
    __shared__ float tile[64][65];
    const int rb = blockIdx.y * 64, cb = blockIdx.x * 64;
    const int t = threadIdx.x;
    const int lr = t >> 4, lc4 = (t & 15) * 4;
#pragma unroll
    for (int i = 0; i < 4; ++i) {
        int r = i * 16 + lr;
        f32x4 v = *(const f32x4*)(in + (size_t)(rb + r) * in_ld + in_off + cb + lc4);
        tile[r][lc4 + 0] = v[0]; tile[r][lc4 + 1] = v[1];
        tile[r][lc4 + 2] = v[2]; tile[r][lc4 + 3] = v[3];
    }
    __syncthreads();
#pragma unroll
    for (int i = 0; i < 4; ++i) {
        int oc = cb + i * 16 + lr;
        u16x4 o;
#pragma unroll
        for (int j = 0; j < 4; ++j)
            o[j] = f32_to_bf16(tile[lc4 + j][i * 16 + lr]);
        *(u16x4*)(out + (size_t)oc * R + rb + lc4) = o;
    }
}

// ------- bf16 [R][in_ld] (col offset in_off) -> bf16 [C][R] -------
__global__ void k_transpose_b16(const unsigned short* __restrict__ in, unsigned short* __restrict__ out,
                                int R, int in_ld, int in_off) {
    __shared__ unsigned short tile[64][68];
    const int rb = blockIdx.y * 64, cb = blockIdx.x * 64;
    const int t = threadIdx.x;
    const int lr = t >> 4, lc4 = (t & 15) * 4;
#pragma unroll
    for (int i = 0; i < 4; ++i) {
        int r = i * 16 + lr;
        u16x4 v = *(const u16x4*)(in + (size_t)(rb + r) * in_ld + in_off + cb + lc4);
        tile[r][lc4 + 0] = v[0]; tile[r][lc4 + 1] = v[1];
        tile[r][lc4 + 2] = v[2]; tile[r][lc4 + 3] = v[3];
    }
    __syncthreads();
#pragma unroll
    for (int i = 0; i < 4; ++i) {
        int oc = cb + i * 16 + lr;
        u16x4 o;
#pragma unroll
        for (int j = 0; j < 4; ++j)
            o[j] = tile[lc4 + j][i * 16 + lr];
        *(u16x4*)(out + (size_t)oc * R + rb + lc4) = o;
    }
}

// ---------------- K-half-phase pipelined bf16 GEMM (round-5 measured-best) ----------------
// C[M][N] = A[M][K] * Bt[N][K]^T.  BM=256, BK=64 (2 K-halves of 32), ring-2.
// LDS slot-swizzle: slot = kchunk ^ (row&3) ^ ((row>>2)&3); staging source pre-swizzled.
// OUT = float (fp32 C) or unsigned short (bf16 C).
template<int BN, typename OUT>
__global__ __launch_bounds__(512, 1)
void k_gemm8p(const unsigned short* __restrict__ A, const unsigned short* __restrict__ Bt,
              OUT* __restrict__ C, int N, int K) {
    constexpr int BH = BN * 32;
    constexpr int NF = BN / 64;
    __shared__ __align__(16) unsigned short As[2][2][8192];
    __shared__ __align__(16) unsigned short Bs[2][2][BH];
    const int tid = threadIdx.x;
    const int lane = tid & 63, wid = tid >> 6;
    const int g = lane >> 4, l15 = lane & 15;
    const int wm = wid >> 2, wn = wid & 3;
    const int nwg = gridDim.x, bid = blockIdx.x;
    const int swz = (bid & 7) * (nwg >> 3) + (bid >> 3);   // bijective: nwg % 8 == 0
    const int ntn = N / BN;
    const int bm = swz / ntn, bn = swz - bm * ntn;
    const int brow = bm << 8, bcol = bn * BN;

    const int rS = tid >> 2;
    const int kcS = (tid & 3) ^ (rS & 3) ^ ((rS >> 2) & 3);
    const unsigned short* sA = A + (size_t)(brow + rS) * K + kcS * 8;
    const unsigned short* sB = Bt + (size_t)(bcol + rS) * K + kcS * 8;
    const int fsw = (g ^ (l15 & 3) ^ ((l15 >> 2) & 3)) * 8;

    f32x4 acc[8][NF] = {};
    const int nt = K >> 6;

    auto stA = [&](int t, int kh) {
        unsigned short* d = &As[t & 1][kh][tid * 8];
        const unsigned short* s = sA + (size_t)t * 64 + kh * 32;
        gload16(s, d);
        gload16(s + (size_t)128 * K, d + 4096);
    };
    auto stB = [&](int t, int kh) {
        unsigned short* d = &Bs[t & 1][kh][tid * 8];
        const unsigned short* s = sB + (size_t)t * 64 + kh * 32;
        gload16(s, d);
        if constexpr (BN == 256) gload16(s + (size_t)128 * K, d + 4096);
    };

    stA(0, 0); stB(0, 0); stA(0, 1); stB(0, 1);

    for (int t = 0; t < nt; ++t) {
        const int c = t & 1;
        if constexpr (BN == 256) {
            s16x8 af[4], bf[4];
            // ---- P0: kh0 x rows 0-63 ----
            if (t + 1 < nt) { stA(t + 1, 0); asm volatile("s_waitcnt vmcnt(6)" ::: "memory"); }
            else            { asm volatile("s_waitcnt vmcnt(4)" ::: "memory"); }
            __builtin_amdgcn_s_barrier();
#pragma unroll
            for (int f = 0; f < 4; ++f)
                af[f] = *(const s16x8*)(&As[c][0][(wm * 128 + f * 16 + l15) * 32 + fsw]);
#pragma unroll
            for (int j = 0; j < 4; ++j)
                bf[j] = *(const s16x8*)(&Bs[c][0][(wn * 64 + j * 16 + l15) * 32 + fsw]);
            __builtin_amdgcn_s_setprio(1);
#pragma unroll
            for (int f = 0; f < 4; ++f)
#pragma unroll
                for (int j = 0; j < 4; ++j)
                    acc[f][j] = __builtin_amdgcn_mfma_f32_16x16x32_bf16(af[f], bf[j], acc[f][j], 0, 0, 0);
            __builtin_amdgcn_s_setprio(0);
            // ---- P1: kh0 x rows 64-127 ----
            if (t + 1 < nt) stB(t + 1, 0);
#pragma unroll
            for (int f = 0; f < 4; ++f)
                af[f] = *(const s16x8*)(&As[c][0][(wm * 128 + 64 + f * 16 + l15) * 32 + fsw]);
            __builtin_amdgcn_s_setprio(1);
#pragma unroll
            for (int f = 0; f < 4; ++f)
#pragma unroll
                for (int j = 0; j < 4; ++j)
                    acc[4 + f][j] = __builtin_amdgcn_mfma_f32_16x16x32_bf16(af[f], bf[j], acc[4 + f][j], 0, 0, 0);
            __builtin_amdgcn_s_setprio(0);
            // ---- P2: kh1 x rows 0-63 ----
            // vmcnt(4): stB(t,1) (consumed HERE) must be complete; only the two
            // stA(t+1,*) pairs may remain outstanding.  (r5 used 6: latent race)
            if (t + 1 < nt) { stA(t + 1, 1); asm volatile("s_waitcnt vmcnt(4)" ::: "memory"); }
            else            { asm volatile("s_waitcnt vmcnt(0)" ::: "memory"); }
            __builtin_amdgcn_s_barrier();
#pragma unroll
            for (int f = 0; f < 4; ++f)
                af[f] = *(const s16x8*)(&As[c][1][(wm * 128 + f * 16 + l15) * 32 + fsw]);
#pragma unroll
            for (int j = 0; j < 4; ++j)
                bf[j] = *(const s16x8*)(&Bs[c][1][(wn * 64 + j * 16 + l15) * 32 + fsw]);
            __builtin_amdgcn_s_setprio(1);
#pragma unroll
            for (int f = 0; f < 4; ++f)
#pragma unroll
                for (int j = 0; j < 4; ++j)
                    acc[f][j] = __builtin_amdgcn_mfma_f32_16x16x32_bf16(af[f], bf[j], acc[f][j], 0, 0, 0);
            __builtin_amdgcn_s_setprio(0);
            // ---- P3: kh1 x rows 64-127 ----
            if (t + 1 < nt) stB(t + 1, 1);
#pragma unroll
            for (int f = 0; f < 4; ++f)
                af[f] = *(const s16x8*)(&As[c][1][(wm * 128 + 64 + f * 16 + l15) * 32 + fsw]);
            __builtin_amdgcn_s_setprio(1);
#pragma unroll
            for (int f = 0; f < 4; ++f)
#pragma unroll
                for (int j = 0; j < 4; ++j)
                    acc[4 + f][j] = __builtin_amdgcn_mfma_f32_16x16x32_bf16(af[f], bf[j], acc[4 + f][j], 0, 0, 0);
            __builtin_amdgcn_s_setprio(0);
        } else {
            s16x8 af[8], bf[2];
            // ---- P0: kh0, all 8 row-frags ----
            if (t + 1 < nt) { stA(t + 1, 0); stB(t + 1, 0); asm volatile("s_waitcnt vmcnt(6)" ::: "memory"); }
            else            { asm volatile("s_waitcnt vmcnt(3)" ::: "memory"); }
            __builtin_amdgcn_s_barrier();
#pragma unroll
            for (int f = 0; f < 8; ++f)
                af[f] = *(const s16x8*)(&As[c][0][(wm * 128 + f * 16 + l15) * 32 + fsw]);
#pragma unroll
            for (int j = 0; j < 2; ++j)
                bf[j] = *(const s16x8*)(&Bs[c][0][(wn * 32 + j * 16 + l15) * 32 + fsw]);
            __builtin_amdgcn_s_setprio(1);
#pragma unroll
            for (int f = 0; f < 8; ++f)
#pragma unroll
                for (int j = 0; j < 2; ++j)
                    acc[f][j] = __builtin_amdgcn_mfma_f32_16x16x32_bf16(af[f], bf[j], acc[f][j], 0, 0, 0);
            __builtin_amdgcn_s_setprio(0);
            // ---- P1: kh1 ----
            if (t + 1 < nt) { stA(t + 1, 1); stB(t + 1, 1); asm volatile("s_waitcnt vmcnt(6)" ::: "memory"); }
            else            { asm volatile("s_waitcnt vmcnt(0)" ::: "memory"); }
            __builtin_amdgcn_s_barrier();
#pragma unroll
            for (int f = 0; f < 8; ++f)
                af[f] = *(const s16x8*)(&As[c][1][(wm * 128 + f * 16 + l15) * 32 + fsw]);
#pragma unroll
            for (int j = 0; j < 2; ++j)
                bf[j] = *(const s16x8*)(&Bs[c][1][(wn * 32 + j * 16 + l15) * 32 + fsw]);
            __builtin_amdgcn_s_setprio(1);
#pragma unroll
            for (int f = 0; f < 8; ++f)
#pragma unroll
                for (int j = 0; j < 2; ++j)
                    acc[f][j] = __builtin_amdgcn_mfma_f32_16x16x32_bf16(af[f], bf[j], acc[f][j], 0, 0, 0);
            __builtin_amdgcn_s_setprio(0);
        }
    }

#pragma unroll
    for (int f = 0; f < 8; ++f)
#pragma unroll
        for (int j = 0; j < NF; ++j)
#pragma unroll
            for (int r = 0; r < 4; ++r) {
                const size_t idx = (size_t)(brow + wm * 128 + f * 16 + g * 4 + r) * N
                                   + bcol + wn * (BN / 4) + j * 16 + l15;
                if constexpr (sizeof(OUT) == 4) C[idx] = acc[f][j][r];
                else                            C[idx] = f32_to_bf16(acc[f][j][r]);
            }
}

// ---------------- vectorized RoPE + pack Q/K (bf16 in, 8 cols/thread) ----------------
// qkv_b [2048][6144] bf16; covers cols 0..5119 (V handled by transpose kernel).
__global__ void k_rope_pack(const unsigned short* __restrict__ qkv, const float* __restrict__ cosT,
                            const float* __restrict__ sinT, unsigned short* __restrict__ Qb,
                            unsigned short* __restrict__ Kb) {
    const int oct = blockIdx.x * 128 + threadIdx.x;   // 0..639
    if (oct >= 640) return;
    const int col = oct * 8;
    const int t = blockIdx.y;
    const int d = col & 127;
    u16x8 v8 = *(const u16x8*)(qkv + (size_t)t * 6144 + col);
    u16x8 o8;
    if (d < 64) {
        u16x8 p8 = *(const u16x8*)(qkv + (size_t)t * 6144 + (col ^ 32));
        f32x4 c0 = *(const f32x4*)(cosT + t * 64 + d);
        f32x4 c1 = *(const f32x4*)(cosT + t * 64 + d + 4);
        f32x4 s0 = *(const f32x4*)(sinT + t * 64 + d);
        f32x4 s1 = *(const f32x4*)(sinT + t * 64 + d + 4);
        const float sgn = (d < 32) ? -1.f : 1.f;
#pragma unroll
        for (int j = 0; j < 8; ++j) {
            float cc = (j < 4) ? c0[j] : c1[j - 4];
            float ss = (j < 4) ? s0[j] : s1[j - 4];
            float o = bf16_to_f32(v8[j]) * cc + sgn * bf16_to_f32(p8[j]) * ss;
            o8[j] = f32_to_bf16(o);
        }
    } else {
        o8 = v8;
    }
    if (col < 4096) {
        const int h = col >> 7;
        *(u16x8*)(Qb + ((size_t)h * 2048 + t) * 128 + d) = o8;
    } else {
        const int hk = (col - 4096) >> 7;
        *(u16x8*)(Kb + ((size_t)hk * 2048 + t) * 128 + d) = o8;
    }
}

// ------- causal GQA flash attention: paired q-tiles (qbA, 31-qbA), shared K/V pass -------
// + T13 defer-max + T5 setprio around MFMA clusters.
__global__ __launch_bounds__(256, 2)
void k_attn(const unsigned short* __restrict__ Qb, const unsigned short* __restrict__ Kb,
            const unsigned short* __restrict__ Vt, unsigned short* __restrict__ Ob) {
    __shared__ __align__(16) unsigned short Ks[2][8192];
    __shared__ __align__(16) unsigned short Vs[2][8192];
    __shared__ __align__(16) unsigned short Pl[2][4][1024];
    const int h = blockIdx.y, hk = h >> 2;
    const int qbA = blockIdx.x, qbB = 31 - qbA;
    const int tid = threadIdx.x, lane = tid & 63, wid = tid >> 6;
    const int g = lane >> 4, l15 = lane & 15;
    const int qrA = qbA * 64 + wid * 16, qrB = qbB * 64 + wid * 16;
    const int swz = (l15 & 7) << 4;

    s16x8 aqA[4], aqB[4];
#pragma unroll
    for (int kc = 0; kc < 4; ++kc) {
        aqA[kc] = *(const s16x8*)(Qb + ((size_t)h * 2048 + qrA + l15) * 128 + kc * 32 + g * 8);
        aqB[kc] = *(const s16x8*)(Qb + ((size_t)h * 2048 + qrB + l15) * 128 + kc * 32 + g * 8);
    }

    const unsigned short* gK = Kb + ((size_t)hk * 2048 + (tid & 63)) * 128 + (tid >> 6) * 8;
    const unsigned short* gV = Vt + ((size_t)hk * 128 + (tid & 127)) * 2048 + (tid >> 7) * 8;

    auto stage = [&](int kb) {
        unsigned short* dK = Ks[kb & 1] + tid * 8;
        unsigned short* dV = Vs[kb & 1] + tid * 8;
        const unsigned short* sK = gK + (size_t)kb * 8192;
        const unsigned short* sV = gV + kb * 64;
#pragma unroll
        for (int i = 0; i < 4; ++i) gload16(sK + i * 32, dK + i * 2048);
#pragma unroll
        for (int i = 0; i < 4; ++i) gload16(sV + i * 16, dV + i * 2048);
    };

    f32x4 oaccA[8] = {}, oaccB[8] = {};
    float mA = -1e30f, lA = 0.f, mB = -1e30f, lB = 0.f;

    auto process = [&](const s16x8* aq, f32x4* oacc, float& mr, float& lr, int qrow0,
                       char* pw, const unsigned short* ks, const unsigned short* vs, int kb) {
        f32x4 s[4] = {};
        __builtin_amdgcn_s_setprio(1);
#pragma unroll
        for (int kc = 0; kc < 4; ++kc)
#pragma unroll
            for (int kt = 0; kt < 4; ++kt) {
                s16x8 kf = *(const s16x8*)(ks + ((kc * 4 + g) * 64 + kt * 16 + l15) * 8);
                s[kt] = __builtin_amdgcn_mfma_f32_16x16x32_bf16(kf, aq[kc], s[kt], 0, 0, 0);
            }
        __builtin_amdgcn_s_setprio(0);
        const int q = qrow0 + l15;
        if (kb * 64 + 63 > qrow0) {
#pragma unroll
            for (int kt = 0; kt < 4; ++kt)
#pragma unroll
                for (int r = 0; r < 4; ++r) {
                    float xv = s[kt][r] * SCALE_F;
                    s[kt][r] = (kb * 64 + kt * 16 + g * 4 + r > q) ? -3e38f : xv;
                }
        } else {
#pragma unroll
            for (int kt = 0; kt < 4; ++kt)
#pragma unroll
                for (int r = 0; r < 4; ++r) s[kt][r] *= SCALE_F;
        }
        float mx = -3e38f;
#pragma unroll
        for (int kt = 0; kt < 4; ++kt)
#pragma unroll
            for (int r = 0; r < 4; ++r) mx = fmaxf(mx, s[kt][r]);
        mx = fmaxf(mx, __shfl_xor(mx, 16));
        mx = fmaxf(mx, __shfl_xor(mx, 32));
        if (!__all(mx - mr <= 8.0f)) {
            const float mnew = fmaxf(mr, mx);
            const float scal = __expf(mr - mnew);
            mr = mnew;
            float so[4];
#pragma unroll
            for (int r = 0; r < 4; ++r) so[r] = __shfl(scal, g * 4 + r, 16);
#pragma unroll
            for (int j = 0; j < 8; ++j) {
                oacc[j][0] *= so[0]; oacc[j][1] *= so[1];
                oacc[j][2] *= so[2]; oacc[j][3] *= so[3];
            }
            lr *= scal;
        }
        float ps = 0.f;
#pragma unroll
        for (int kt = 0; kt < 4; ++kt)
#pragma unroll
            for (int r = 0; r < 4; ++r) {
                float p = __expf(s[kt][r] - mr);
                s[kt][r] = p;
                ps += p;
            }
        ps += __shfl_xor(ps, 16);
        ps += __shfl_xor(ps, 32);
        lr += ps;
#pragma unroll
        for (int kt = 0; kt < 4; ++kt) {
            unsigned int w0 = (unsigned int)f32_to_bf16(s[kt][0]) | ((unsigned int)f32_to_bf16(s[kt][1]) << 16);
            unsigned int w1 = (unsigned int)f32_to_bf16(s[kt][2]) | ((unsigned int)f32_to_bf16(s[kt][3]) << 16);
            const int b0 = (l15 * 128 + kt * 32 + g * 8) ^ swz;
            *(unsigned int*)(pw + b0) = w0;
            *(unsigned int*)(pw + b0 + 4) = w1;
        }
        __builtin_amdgcn_s_setprio(1);
#pragma unroll
        for (int kc = 0; kc < 2; ++kc) {
            s16x8 pa = *(const s16x8*)(pw + ((l15 * 128 + kc * 64 + g * 16) ^ swz));
#pragma unroll
            for (int j = 0; j < 8; ++j) {
                s16x8 bv = *(const s16x8*)(vs + ((kc * 4 + g) * 128 + j * 16 + l15) * 8);
                oacc[j] = __builtin_amdgcn_mfma_f32_16x16x32_bf16(pa, bv, oacc[j], 0, 0, 0);
            }
        }
        __builtin_amdgcn_s_setprio(0);
    };

    const int nkb = qbB + 1;
    stage(0);
    for (int kb = 0; kb < nkb; ++kb) {
        if (kb + 1 < nkb) {
            stage(kb + 1);
            asm volatile("s_waitcnt vmcnt(8)" ::: "memory");
        } else {
            asm volatile("s_waitcnt vmcnt(0)" ::: "memory");
        }
        __builtin_amdgcn_s_barrier();
        const unsigned short* ks = Ks[kb & 1];
        const unsigned short* vs = Vs[kb & 1];
        process(aqB, oaccB, mB, lB, qrB, (char*)Pl[1][wid], ks, vs, kb);
        if (kb <= qbA)
            process(aqA, oaccA, mA, lA, qrA, (char*)Pl[0][wid], ks, vs, kb);
        __builtin_amdgcn_s_barrier();
    }
    float liA[4], liB[4];
#pragma unroll
    for (int r = 0; r < 4; ++r) {
        liA[r] = 1.f / __shfl(lA, g * 4 + r, 16);
        liB[r] = 1.f / __shfl(lB, g * 4 + r, 16);
    }
#pragma unroll
    for (int j = 0; j < 8; ++j)
#pragma unroll
        for (int r = 0; r < 4; ++r) {
            Ob[(size_t)(qrA + g * 4 + r) * 4096 + h * 128 + j * 16 + l15] = f32_to_bf16(oaccA[j][r] * liA[r]);
            Ob[(size_t)(qrB + g * 4 + r) * 4096 + h * 128 + j * 16 + l15] = f32_to_bf16(oaccB[j][r] * liB[r]);
        }
}

extern "C" void kernel_launch(void* const* d_in, const int* in_sizes, int n_in,
                              void* d_out, int out_size, void* d_ws, size_t ws_size,
                              hipStream_t stream) {
    const float* x     = (const float*)d_in[0];
    const float* cosT  = (const float*)d_in[2];
    const float* sinT  = (const float*)d_in[3];
    const float* w_qkv = (const float*)d_in[4];
    const float* w_o   = (const float*)d_in[5];
    float* out = (float*)d_out;

    char* ws = (char*)d_ws;
    unsigned short* wT   = (unsigned short*)(ws + 0);           // 50.3 MB (w_qkv^T / w_o^T)
    unsigned short* qkvb = (unsigned short*)(ws + 50331648);    // 25.2 MB bf16 qkv
    unsigned short* Ob   = (unsigned short*)(ws + 50331648);    // reuse after rope+t_V
    unsigned short* xb   = (unsigned short*)(ws + 100663296);   // 16.8 MB
    unsigned short* Qb   = xb;                                  // reuse after gemmA
    unsigned short* Kb   = (unsigned short*)(ws + 117440512);   // 4.2 MB
    unsigned short* Vt   = (unsigned short*)(ws + 121634816);   // 4.2 MB

    k_conv_bf16<<<8192, 256, 0, stream>>>(x, xb, 2097152);
    k_transpose_f32<<<dim3(96, 64), 256, 0, stream>>>(w_qkv, wT, 4096, 6144, 0);
    k_gemm8p<256, unsigned short><<<192, 512, 0, stream>>>(xb, wT, qkvb, 6144, 4096);
    k_rope_pack<<<dim3(5, 2048), 128, 0, stream>>>(qkvb, cosT, sinT, Qb, Kb);
    k_transpose_b16<<<dim3(16, 32), 256, 0, stream>>>(qkvb, Vt, 2048, 6144, 5120);   // V^T
    k_transpose_f32<<<dim3(64, 64), 256, 0, stream>>>(w_o, wT, 4096, 4096, 0);
    k_attn<<<dim3(16, 32), 256, 0, stream>>>(Qb, Kb, Vt, Ob);
    k_gemm8p<128, float><<<256, 512, 0, stream>>>(Ob, wT, out, 4096, 4096);
}